// Round 7
// baseline (325.041 us; speedup 1.0000x reference)
//
#include <hip/hip_runtime.h>

#define DEV __device__ __forceinline__

constexpr int Bc = 2, Tc = 128, Dc = 256, Lc = 8, Hc = 4, DH = 64, Fc = 2048;
constexpr float EPS = 1e-5f, SCALE = 0.125f;  // 1/sqrt(64)
constexpr int NROWS = Bc * Tc * Lc;           // 2048 candidate rows
constexpr int SLAB = NROWS * Dc;              // 524288 floats

// ---- workspace layout (float offsets) ----
constexpr int OFF_K     = 0;                        // B*T*D frame keys
constexpr int OFF_VWOH  = OFF_K + Bc * Tc * Dc;     // B*T*H*D per-head v@Wo partials
constexpr int OFF_QCLS  = OFF_VWOH + Bc * Tc * Hc * Dc;
constexpr int OFF_KCLS  = OFF_QCLS + Dc;
constexpr int OFF_VWOHC = OFF_KCLS + Dc;            // H*D
constexpr int OFF_ENC   = OFF_VWOHC + Hc * Dc;      // B*T*L*D x0, then enc (in-place)
constexpr int OFF_Z     = OFF_ENC + SLAB;           // B*T*L eoc logits
constexpr int OFF_H2    = OFF_Z + NROWS;            // B*T*L*D ln2 rows
constexpr int OFF_U     = OFF_H2 + SLAB;            // G partial-U slabs [G][NROWS][D]

constexpr int RB = 16;                 // rows per FFN block (32KB LDS -> 4 blocks/CU)
constexpr int GSPLIT = 8;              // F-dimension split (preserves U0..U7 sum order)
constexpr int FS = Fc / GSPLIT;        // 256 f-cols per slice
constexpr int NRB = NROWS / RB;        // 128 row-blocks
constexpr int NT_FZ = NRB * GSPLIT;    // 1024 blocks

constexpr int OFF_CNT = OFF_U + GSPLIT * SLAB;  // NRB rb-counters + 1 emit counter

DEV int imin(int a, int b) { return a < b ? a : b; }

// block = 256 threads (4 waves). red must be shared float[4].
DEV float blockReduceSum(float v, float* red) {
#pragma unroll
  for (int off = 32; off; off >>= 1) v += __shfl_down(v, off, 64);
  const int lane = threadIdx.x & 63;
  const int w = threadIdx.x >> 6;
  __syncthreads();  // protect red from previous use
  if (lane == 0) red[w] = v;
  __syncthreads();
  return red[0] + red[1] + red[2] + red[3];
}

// ---- K1: one row per block. LN1 + k/v projections + per-head v@Wo; q for CLS row.
//      Also zeroes the completion counters (main path only). ----
__global__ __launch_bounds__(256) void k_prep(
    const float* __restrict__ frames, const float* __restrict__ cls,
    const float* __restrict__ Wq, const float* __restrict__ bq,
    const float* __restrict__ Wk, const float* __restrict__ bk,
    const float* __restrict__ Wv, const float* __restrict__ bv,
    const float* __restrict__ Wo,
    const float* __restrict__ g1, const float* __restrict__ b1,
    float* __restrict__ ws, int zero_cnt) {
  __shared__ float hsm[Dc];
  __shared__ float vsm[Dc];
  __shared__ float red[4];
  const int d = threadIdx.x;
  const int r = blockIdx.x;  // 0..B*T-1 frames, B*T = cls

  if (zero_cnt && d == 0 && r <= NRB) {
    reinterpret_cast<int*>(ws + OFF_CNT)[r] = 0;   // cnt[0..NRB-1] + emit counter
  }

  const float x = (r < Bc * Tc) ? frames[r * Dc + d] : cls[d];
  const float s = blockReduceSum(x, red);
  const float m = s * (1.0f / Dc);
  const float c = x - m;
  const float var = blockReduceSum(c * c, red) * (1.0f / Dc);
  hsm[d] = c * (1.0f / sqrtf(var + EPS)) * g1[d] + b1[d];
  __syncthreads();

  float ka = bk[d], va = bv[d];
  for (int c2 = 0; c2 < Dc; ++c2) {
    const float h = hsm[c2];
    ka = fmaf(h, Wk[c2 * Dc + d], ka);
    va = fmaf(h, Wv[c2 * Dc + d], va);
  }
  if (r < Bc * Tc) ws[OFF_K + r * Dc + d] = ka;
  else             ws[OFF_KCLS + d] = ka;
  vsm[d] = va;
  __syncthreads();

#pragma unroll
  for (int hh = 0; hh < Hc; ++hh) {
    float acc = 0.f;
    for (int c2 = 0; c2 < DH; ++c2)
      acc = fmaf(vsm[hh * DH + c2], Wo[(hh * DH + c2) * Dc + d], acc);
    if (r < Bc * Tc) ws[OFF_VWOH + r * (Hc * Dc) + hh * Dc + d] = acc;
    else             ws[OFF_VWOHC + hh * Dc + d] = acc;
  }
  if (r == Bc * Tc) {
    float qa = bq[d];
    for (int c2 = 0; c2 < Dc; ++c2) qa = fmaf(hsm[c2], Wq[c2 * Dc + d], qa);
    ws[OFF_QCLS + d] = qa;
  }
}

// ---- K2: per (b,i): scores + softmax + x0 + LN2 -> h2 slab, x0 slab. 256 thr. ----
__global__ __launch_bounds__(256) void k_attn(
    const float* __restrict__ cls, const float* __restrict__ bo,
    const float* __restrict__ g2, const float* __restrict__ b2,
    float* __restrict__ ws) {
  const int wg = blockIdx.x;  // b*T + i
  const int i = wg & (Tc - 1);
  const int tid = threadIdx.x;
  const int lane = tid & 63;
  const int lmax = imin(Tc - i, Lc);

  __shared__ float sv[Hc][Lc + 1];
  __shared__ float aP[Lc][Hc][Lc + 1];
  __shared__ __align__(16) float redA[Lc][4];
  __shared__ __align__(16) float redB[Lc][4];

  {
    const int hh = tid >> 6;
    const float qv = ws[OFF_QCLS + hh * DH + lane];
    for (int j = 0; j <= Lc; ++j) {
      float p = 0.f;
      if (j == 0) p = qv * ws[OFF_KCLS + hh * DH + lane];
      else if (j - 1 < lmax) p = qv * ws[OFF_K + (wg + j - 1) * Dc + hh * DH + lane];
#pragma unroll
      for (int off = 32; off; off >>= 1) p += __shfl_down(p, off, 64);
      if (lane == 0) sv[hh][j] = p * SCALE;
    }
  }
  __syncthreads();

  if (tid < Lc * Hc) {
    const int l = (tid >> 2) + 1, h4 = tid & 3;
    if (l <= lmax) {
      float mx = -1e30f;
      for (int j = 0; j <= l; ++j) mx = fmaxf(mx, sv[h4][j]);
      float den = 0.f;
      for (int j = 0; j <= l; ++j) den += expf(sv[h4][j] - mx);
      const float inv = 1.f / den;
      for (int j = 0; j <= l; ++j) aP[l - 1][h4][j] = expf(sv[h4][j] - mx) * inv;
    }
  }
  __syncthreads();

  const int d = tid;
  float x0v[Lc];
  {
    const float base = cls[d] + bo[d];
#pragma unroll
    for (int l = 0; l < Lc; ++l) x0v[l] = base;
    for (int j = 0; j <= lmax; ++j) {
      const float* vwp = (j == 0) ? (ws + OFF_VWOHC)
                                  : (ws + OFF_VWOH + (wg + j - 1) * (Hc * Dc));
      for (int h4 = 0; h4 < Hc; ++h4) {
        const float w = vwp[h4 * Dc + d];
        const int lstart = (j == 0) ? 1 : j;
        for (int l = lstart; l <= lmax; ++l) x0v[l - 1] = fmaf(aP[l - 1][h4][j], w, x0v[l - 1]);
      }
    }
#pragma unroll
    for (int l = 0; l < Lc; ++l) {
      float p = x0v[l];
#pragma unroll
      for (int off = 32; off; off >>= 1) p += __shfl_down(p, off, 64);
      if (lane == 0) redA[l][tid >> 6] = p;
    }
  }
  __syncthreads();

  float mean[Lc];
  {
#pragma unroll
    for (int l = 0; l < Lc; ++l) {
      const float4 s4 = *(const float4*)redA[l];
      mean[l] = (s4.x + s4.y + s4.z + s4.w) * (1.f / Dc);
    }
#pragma unroll
    for (int l = 0; l < Lc; ++l) {
      const float cv = x0v[l] - mean[l];
      float p = cv * cv;
#pragma unroll
      for (int off = 32; off; off >>= 1) p += __shfl_down(p, off, 64);
      if (lane == 0) redB[l][tid >> 6] = p;
    }
  }
  __syncthreads();

  {
    const float g2d = g2[d], b2d = b2[d];
    for (int l = 1; l <= lmax; ++l) {
      const float4 s4 = *(const float4*)redB[l - 1];
      const float var = (s4.x + s4.y + s4.z + s4.w) * (1.f / Dc);
      const float rstd = 1.f / sqrtf(var + EPS);
      ws[OFF_H2 + (wg * Lc + l - 1) * Dc + d] = (x0v[l - 1] - mean[l - 1]) * rstd * g2d + b2d;
      ws[OFF_ENC + (wg * Lc + l - 1) * Dc + d] = x0v[l - 1];
    }
    for (int l = lmax + 1; l <= Lc; ++l) {
      ws[OFF_H2 + (wg * Lc + l - 1) * Dc + d] = 0.f;
      ws[OFF_ENC + (wg * Lc + l - 1) * Dc + d] = 0.f;
    }
  }
}

// ---- K3: batched FFN (R6-verified GEMM body) + z tail per rb-finisher + emit tail.
//      Fence discipline (the R5 lesson): publishers use RELEASE-ONLY atomics
//      (writeback, no invalidate -> W1/W2 stay hot in L2 for running blocks);
//      only the 128 finishers + 1 emit-finisher execute an acquire fence. ----
struct FZmain { float h2s[RB][Dc]; float Ts[RB][FS]; };     // 16KB + 16KB
struct FZz    { float encs[Lc][Dc]; float zred[2][4][4]; }; // 8KB
struct FZe    { int lst[Tc]; int path[Tc]; int cnt; };
union  FZu    { FZmain m; FZz z; FZe e; };

__global__ __launch_bounds__(256, 4) void k_fzze(
    const float* __restrict__ W1, const float* __restrict__ b1f,
    const float* __restrict__ W2, const float* __restrict__ b2f,
    const float* __restrict__ We1, const float* __restrict__ be1,
    const float* __restrict__ We2, const float* __restrict__ be2,
    float* __restrict__ ws, float* __restrict__ out) {
  const int rb = blockIdx.x >> 3;   // row-block 0..127
  const int g = blockIdx.x & 7;     // F-slice; round-robin XCD dispatch => per-XCD
                                    // L2 sees mostly one 0.5MB weight slice
  const int r0 = rb * RB;
  const int tid = threadIdx.x;
  const int lane = tid & 63;
  const int cg = tid & 63;
  const int rg = tid >> 6;

  __shared__ __align__(16) FZu sm;
  __shared__ int flag;

  // stage h2 rows [r0, r0+16)
#pragma unroll
  for (int it = 0; it < 4; ++it) {
    const int row = it * 4 + rg;
    *(float4*)&sm.m.h2s[row][cg * 4] =
        *(const float4*)&ws[OFF_H2 + (r0 + row) * Dc + cg * 4];
  }
  __syncthreads();

  // ---- GEMM1: T = relu(h2 @ W1_slice + b1f); 8-deep batches + 1-deep prefetch ----
  const int f0 = g * FS + cg * 4;
  {
    float t[4][4];
    {
      const float4 bb = *(const float4*)&b1f[f0];
#pragma unroll
      for (int r = 0; r < 4; ++r) { t[r][0] = bb.x; t[r][1] = bb.y; t[r][2] = bb.z; t[r][3] = bb.w; }
    }
    const float* Wp = W1 + f0;
    float4 wn[8];
#pragma unroll
    for (int k = 0; k < 8; ++k) wn[k] = *(const float4*)&Wp[k * Fc];
    for (int c = 0; c < Dc; c += 8) {
      float4 wc[8];
#pragma unroll
      for (int k = 0; k < 8; ++k) wc[k] = wn[k];
      {  // branchless 1-deep prefetch (re-reads last rows on final iter)
        const float* Wn = Wp + imin(c + 8, Dc - 8) * Fc;
#pragma unroll
        for (int k = 0; k < 8; ++k) wn[k] = *(const float4*)&Wn[k * Fc];
      }
#pragma unroll
      for (int r = 0; r < 4; ++r) {
        const float4 ha = *(const float4*)&sm.m.h2s[rg * 4 + r][c];
        const float4 hb = *(const float4*)&sm.m.h2s[rg * 4 + r][c + 4];
        const float hv[8] = {ha.x, ha.y, ha.z, ha.w, hb.x, hb.y, hb.z, hb.w};
#pragma unroll
        for (int k = 0; k < 8; ++k) {
          t[r][0] = fmaf(hv[k], wc[k].x, t[r][0]);
          t[r][1] = fmaf(hv[k], wc[k].y, t[r][1]);
          t[r][2] = fmaf(hv[k], wc[k].z, t[r][2]);
          t[r][3] = fmaf(hv[k], wc[k].w, t[r][3]);
        }
      }
    }
#pragma unroll
    for (int r = 0; r < 4; ++r) {
      float4 v;
      v.x = fmaxf(t[r][0], 0.f); v.y = fmaxf(t[r][1], 0.f);
      v.z = fmaxf(t[r][2], 0.f); v.w = fmaxf(t[r][3], 0.f);
      *(float4*)&sm.m.Ts[rg * 4 + r][cg * 4] = v;
    }
  }
  __syncthreads();

  // ---- GEMM2: U_partial = T @ W2_slice ----
  {
    float u[4][4];
#pragma unroll
    for (int r = 0; r < 4; ++r) { u[r][0] = 0.f; u[r][1] = 0.f; u[r][2] = 0.f; u[r][3] = 0.f; }
    const float* Wp = W2 + g * FS * Dc + cg * 4;
    float4 wn[8];
#pragma unroll
    for (int k = 0; k < 8; ++k) wn[k] = *(const float4*)&Wp[k * Dc];
    for (int kk = 0; kk < FS; kk += 8) {
      float4 wc[8];
#pragma unroll
      for (int k = 0; k < 8; ++k) wc[k] = wn[k];
      {
        const float* Wn = Wp + imin(kk + 8, FS - 8) * Dc;
#pragma unroll
        for (int k = 0; k < 8; ++k) wn[k] = *(const float4*)&Wn[k * Dc];
      }
#pragma unroll
      for (int r = 0; r < 4; ++r) {
        const float4 aa = *(const float4*)&sm.m.Ts[rg * 4 + r][kk];
        const float4 ab = *(const float4*)&sm.m.Ts[rg * 4 + r][kk + 4];
        const float av[8] = {aa.x, aa.y, aa.z, aa.w, ab.x, ab.y, ab.z, ab.w};
#pragma unroll
        for (int k = 0; k < 8; ++k) {
          u[r][0] = fmaf(av[k], wc[k].x, u[r][0]);
          u[r][1] = fmaf(av[k], wc[k].y, u[r][1]);
          u[r][2] = fmaf(av[k], wc[k].z, u[r][2]);
          u[r][3] = fmaf(av[k], wc[k].w, u[r][3]);
        }
      }
    }
#pragma unroll
    for (int r = 0; r < 4; ++r) {
      float4 v; v.x = u[r][0]; v.y = u[r][1]; v.z = u[r][2]; v.w = u[r][3];
      *(float4*)&ws[OFF_U + (g * NROWS + r0 + rg * 4 + r) * Dc + cg * 4] = v;
    }
  }

  // ---- publish: release-only (no invalidate; W stays cached for other blocks) ----
  int* cnt = reinterpret_cast<int*>(ws + OFF_CNT);
  __syncthreads();  // all U stores issued+drained within block
  if (tid == 0) {
    const int old = __hip_atomic_fetch_add(&cnt[rb], 1, __ATOMIC_RELEASE,
                                           __HIP_MEMORY_SCOPE_AGENT);
    flag = (old == GSPLIT - 1);
  }
  __syncthreads();
  if (!flag) return;
  if (tid == 0) __builtin_amdgcn_fence(__ATOMIC_ACQUIRE, "agent");  // inv once
  __syncthreads();

  // ---- z tail (R5-verified chains): enc + z for this rb's 2 (b,i) groups ----
  const int wv = tid >> 6;
  for (int grp = 0; grp < 2; ++grp) {
    __syncthreads();
    const int wg = rb * 2 + grp;
#pragma unroll
    for (int half = 0; half < 2; ++half) {
      const int r = half * 4 + wv;       // rows 0..7
      const int dg = lane * 4;
      const int row = wg * Lc + r;
      float4 s = *(const float4*)&ws[OFF_U + (0 * NROWS + row) * Dc + dg];
#pragma unroll
      for (int gg = 1; gg < GSPLIT; ++gg) {
        const float4 p = *(const float4*)&ws[OFF_U + (gg * NROWS + row) * Dc + dg];
        s.x += p.x; s.y += p.y; s.z += p.z; s.w += p.w;
      }
      const float4 x0 = *(const float4*)&ws[OFF_ENC + row * Dc + dg];
      const float4 bb = *(const float4*)&b2f[dg];
      float4 e;
      e.x = (x0.x + s.x) + bb.x; e.y = (x0.y + s.y) + bb.y;
      e.z = (x0.z + s.z) + bb.z; e.w = (x0.w + s.w) + bb.w;
      *(float4*)&ws[OFF_ENC + row * Dc + dg] = e;
      *(float4*)&sm.z.encs[r][dg] = e;
    }
    __syncthreads();

    {
      const int f = tid;
      const float be1f = be1[f];
      const float w2v = We2[f];
#pragma unroll
      for (int rh = 0; rh < 2; ++rh) {
        float gr[4];
#pragma unroll
        for (int rr = 0; rr < 4; ++rr) gr[rr] = be1f;
        for (int c = 0; c < Dc; c += 4) {
          const float w0 = We1[(c + 0) * Dc + f];
          const float w1 = We1[(c + 1) * Dc + f];
          const float w2 = We1[(c + 2) * Dc + f];
          const float w3 = We1[(c + 3) * Dc + f];
#pragma unroll
          for (int rr = 0; rr < 4; ++rr) {
            const float4 e = *(const float4*)&sm.z.encs[rh * 4 + rr][c];
            gr[rr] = fmaf(e.x, w0, gr[rr]);
            gr[rr] = fmaf(e.y, w1, gr[rr]);
            gr[rr] = fmaf(e.z, w2, gr[rr]);
            gr[rr] = fmaf(e.w, w3, gr[rr]);
          }
        }
#pragma unroll
        for (int rr = 0; rr < 4; ++rr) {
          float p = fmaxf(gr[rr], 0.f) * w2v;
#pragma unroll
          for (int off = 32; off; off >>= 1) p += __shfl_down(p, off, 64);
          if (lane == 0) sm.z.zred[rh][wv][rr] = p;
        }
      }
    }
    __syncthreads();
    if (tid < 8) {
      const int r = tid;
      const int rh = r >> 2, rl = r & 3;
      const float z = ((sm.z.zred[rh][0][rl] + sm.z.zred[rh][1][rl]) + sm.z.zred[rh][2][rl]) +
                      sm.z.zred[rh][3][rl];
      ws[OFF_Z + wg * 8 + r] = z + be2[0];
    }
  }

  // ---- emit tail: last of the 128 finishers emits both batches ----
  __syncthreads();  // z stores issued
  if (tid == 0) {
    const int old2 = __hip_atomic_fetch_add(&cnt[NRB], 1, __ATOMIC_RELEASE,
                                            __HIP_MEMORY_SCOPE_AGENT);
    flag = (old2 == NRB - 1);
  }
  __syncthreads();
  if (!flag) return;
  if (tid == 0) __builtin_amdgcn_fence(__ATOMIC_ACQUIRE, "agent");
  __syncthreads();

  for (int b = 0; b < Bc; ++b) {
    __syncthreads();
    if (tid < Tc) {
      const int i = tid;
      const int lmax = imin(Tc - i, Lc);
      const float* z = ws + OFF_Z + (b * Tc + i) * Lc;
      int ls = lmax;
      for (int l = 1; l <= lmax; ++l) {
        if (z[l - 1] > 0.f) { ls = l; break; }
      }
      sm.e.lst[tid] = ls;
    }
    __syncthreads();
    if (tid < 64) {  // wave 0: walk via register shuffles
      const int a0 = sm.e.lst[tid], a1 = sm.e.lst[64 + tid];
      int cur = 0, n = 0;
      while (cur < Tc) {
        const int l = (cur < 64) ? __shfl(a0, cur, 64) : __shfl(a1, cur - 64, 64);
        if (tid == 0) sm.e.path[n] = cur * Lc + l - 1;
        ++n;
        cur += l;
      }
      if (tid == 0) sm.e.cnt = n;
    }
    __syncthreads();
    const int c = sm.e.cnt;
    for (int s0 = 0; s0 < Tc; s0 += 8) {
      float v[8];
#pragma unroll
      for (int k = 0; k < 8; ++k) {
        const int st = s0 + k;
        v[k] = (st < c) ? ws[OFF_ENC + (b * Tc * Lc + sm.e.path[st]) * Dc + tid] : 0.f;
      }
#pragma unroll
      for (int k = 0; k < 8; ++k) out[(b * Tc + s0 + k) * Dc + tid] = v[k];
    }
    if (tid == 0) out[Bc * Tc * Dc + b] = (float)c;
  }
}

// ---- standalone emit (fallback path) ----
__global__ __launch_bounds__(256) void k_emit(float* __restrict__ ws, float* __restrict__ out) {
  const int b = blockIdx.x;
  const int tid = threadIdx.x;
  __shared__ int lst[Tc];
  __shared__ int path[Tc];
  __shared__ int cnt_s;
  if (tid < Tc) {
    const int i = tid;
    const int lmax = imin(Tc - i, Lc);
    const float* z = ws + OFF_Z + (b * Tc + i) * Lc;
    int ls = lmax;
    for (int l = 1; l <= lmax; ++l) {
      if (z[l - 1] > 0.f) { ls = l; break; }
    }
    lst[tid] = ls;
  }
  __syncthreads();
  if (tid < 64) {
    const int a0 = lst[tid], a1 = lst[64 + tid];
    int cur = 0, s = 0;
    while (cur < Tc) {
      const int l = (cur < 64) ? __shfl(a0, cur, 64) : __shfl(a1, cur - 64, 64);
      if (tid == 0) path[s] = cur * Lc + l - 1;
      ++s;
      cur += l;
    }
    if (tid == 0) cnt_s = s;
  }
  __syncthreads();
  const int c = cnt_s;
  for (int s0 = 0; s0 < Tc; s0 += 8) {
    float v[8];
#pragma unroll
    for (int k = 0; k < 8; ++k) {
      const int s = s0 + k;
      v[k] = (s < c) ? ws[OFF_ENC + (b * Tc * Lc + path[s]) * Dc + tid] : 0.f;
    }
#pragma unroll
    for (int k = 0; k < 8; ++k) out[(b * Tc + s0 + k) * Dc + tid] = v[k];
  }
  if (tid == 0) out[Bc * Tc * Dc + b] = (float)c;
}

// ---- tiny-workspace fallback: round-0 fully-fused K2 (verified) ----
__global__ __launch_bounds__(512) void k_fused(
    const float* __restrict__ cls, const float* __restrict__ bo,
    const float* __restrict__ g2, const float* __restrict__ b2,
    const float* __restrict__ W1, const float* __restrict__ b1f,
    const float* __restrict__ W2, const float* __restrict__ b2f,
    const float* __restrict__ We1, const float* __restrict__ be1,
    const float* __restrict__ We2, const float* __restrict__ be2,
    float* __restrict__ ws) {
  const int wg = blockIdx.x;
  const int i = wg & (Tc - 1);
  const int tid = threadIdx.x;
  const int wv = tid >> 6, lane = tid & 63;
  const int lmax = imin(Tc - i, Lc);

  __shared__ __align__(16) float ts[8][2048];
  __shared__ __align__(16) float h2s[8][256];
  __shared__ __align__(16) float x0s[8][256];
  __shared__ __align__(16) float encs[8][256];
  __shared__ float sv[Hc][Lc + 1];
  __shared__ float aP[Lc][Hc][Lc + 1];
  __shared__ __align__(16) float redA[Lc][4];
  __shared__ __align__(16) float redB[Lc][4];
  __shared__ float zred[8][4];

  if (tid < 256) {
    const int hh = tid >> 6;
    const float qv = ws[OFF_QCLS + hh * DH + lane];
    for (int j = 0; j <= Lc; ++j) {
      float p = 0.f;
      if (j == 0) p = qv * ws[OFF_KCLS + hh * DH + lane];
      else if (j - 1 < lmax) p = qv * ws[OFF_K + (wg + j - 1) * Dc + hh * DH + lane];
#pragma unroll
      for (int off = 32; off; off >>= 1) p += __shfl_down(p, off, 64);
      if (lane == 0) sv[hh][j] = p * SCALE;
    }
  }
  __syncthreads();

  if (tid < Lc * Hc) {
    const int l = (tid >> 2) + 1, h4 = tid & 3;
    if (l <= lmax) {
      float mx = -1e30f;
      for (int j = 0; j <= l; ++j) mx = fmaxf(mx, sv[h4][j]);
      float den = 0.f;
      for (int j = 0; j <= l; ++j) den += expf(sv[h4][j] - mx);
      const float inv = 1.f / den;
      for (int j = 0; j <= l; ++j) aP[l - 1][h4][j] = expf(sv[h4][j] - mx) * inv;
    }
  }
  __syncthreads();

  float x0v[Lc];
  if (tid < 256) {
    const int d = tid;
    const float base = cls[d] + bo[d];
#pragma unroll
    for (int l = 0; l < Lc; ++l) x0v[l] = base;
    for (int j = 0; j <= lmax; ++j) {
      const float* vwp = (j == 0) ? (ws + OFF_VWOHC)
                                  : (ws + OFF_VWOH + (wg + j - 1) * (Hc * Dc));
      for (int h4 = 0; h4 < Hc; ++h4) {
        const float w = vwp[h4 * Dc + d];
        const int lstart = (j == 0) ? 1 : j;
        for (int l = lstart; l <= lmax; ++l) x0v[l - 1] = fmaf(aP[l - 1][h4][j], w, x0v[l - 1]);
      }
    }
#pragma unroll
    for (int l = 0; l < Lc; ++l) {
      float p = x0v[l];
#pragma unroll
      for (int off = 32; off; off >>= 1) p += __shfl_down(p, off, 64);
      if (lane == 0) redA[l][tid >> 6] = p;
    }
  }
  __syncthreads();

  float mean[Lc];
  if (tid < 256) {
#pragma unroll
    for (int l = 0; l < Lc; ++l) {
      const float4 s4 = *(const float4*)redA[l];
      mean[l] = (s4.x + s4.y + s4.z + s4.w) * (1.f / Dc);
    }
#pragma unroll
    for (int l = 0; l < Lc; ++l) {
      const float cv = x0v[l] - mean[l];
      float p = cv * cv;
#pragma unroll
      for (int off = 32; off; off >>= 1) p += __shfl_down(p, off, 64);
      if (lane == 0) redB[l][tid >> 6] = p;
    }
  }
  __syncthreads();

  if (tid < 256) {
    const int d = tid;
    const float g2d = g2[d], b2d = b2[d];
    for (int l = 1; l <= lmax; ++l) {
      const float4 s4 = *(const float4*)redB[l - 1];
      const float var = (s4.x + s4.y + s4.z + s4.w) * (1.f / Dc);
      const float rstd = 1.f / sqrtf(var + EPS);
      h2s[l - 1][d] = (x0v[l - 1] - mean[l - 1]) * rstd * g2d + b2d;
      x0s[l - 1][d] = x0v[l - 1];
    }
    for (int l = lmax + 1; l <= Lc; ++l) {
      h2s[l - 1][d] = 0.f;
      x0s[l - 1][d] = 0.f;
    }
  }
  __syncthreads();

  const int fg = tid * 4;
  float t[8][4];
  {
    const float4 bb = *(const float4*)&b1f[fg];
#pragma unroll
    for (int r = 0; r < 8; ++r) { t[r][0] = bb.x; t[r][1] = bb.y; t[r][2] = bb.z; t[r][3] = bb.w; }
  }
  for (int c = 0; c < Dc; c += 4) {
    float4 w1v[4];
#pragma unroll
    for (int k = 0; k < 4; ++k) w1v[k] = *(const float4*)&W1[(c + k) * Fc + fg];
#pragma unroll
    for (int r = 0; r < 8; ++r) {
      const float4 h = *(const float4*)&h2s[r][c];
      const float hv[4] = {h.x, h.y, h.z, h.w};
#pragma unroll
      for (int k = 0; k < 4; ++k) {
        t[r][0] = fmaf(hv[k], w1v[k].x, t[r][0]);
        t[r][1] = fmaf(hv[k], w1v[k].y, t[r][1]);
        t[r][2] = fmaf(hv[k], w1v[k].z, t[r][2]);
        t[r][3] = fmaf(hv[k], w1v[k].w, t[r][3]);
      }
    }
  }
#pragma unroll
  for (int r = 0; r < 8; ++r) {
    float4 v;
    v.x = fmaxf(t[r][0], 0.f); v.y = fmaxf(t[r][1], 0.f);
    v.z = fmaxf(t[r][2], 0.f); v.w = fmaxf(t[r][3], 0.f);
    *(float4*)&ts[r][fg] = v;
  }
  __syncthreads();

  const int d4 = lane * 4;
  float u[8][4];
#pragma unroll
  for (int r = 0; r < 8; ++r) { u[r][0] = 0.f; u[r][1] = 0.f; u[r][2] = 0.f; u[r][3] = 0.f; }
  for (int kk = 0; kk < 256; kk += 4) {
    const int kg = wv * 256 + kk;
    float4 w2v[4];
#pragma unroll
    for (int k = 0; k < 4; ++k) w2v[k] = *(const float4*)&W2[(kg + k) * Dc + d4];
#pragma unroll
    for (int r = 0; r < 8; ++r) {
      const float4 h = *(const float4*)&ts[r][kg];
      const float hv[4] = {h.x, h.y, h.z, h.w};
#pragma unroll
      for (int k = 0; k < 4; ++k) {
        u[r][0] = fmaf(hv[k], w2v[k].x, u[r][0]);
        u[r][1] = fmaf(hv[k], w2v[k].y, u[r][1]);
        u[r][2] = fmaf(hv[k], w2v[k].z, u[r][2]);
        u[r][3] = fmaf(hv[k], w2v[k].w, u[r][3]);
      }
    }
  }
  __syncthreads();

  float* redb = &ts[0][0];
#pragma unroll
  for (int r = 0; r < 8; ++r) {
    float4 v; v.x = u[r][0]; v.y = u[r][1]; v.z = u[r][2]; v.w = u[r][3];
    *(float4*)&redb[(wv * 8 + r) * 256 + d4] = v;
  }
  __syncthreads();

  {
    const int r = tid >> 6;
    const int dg = (tid & 63) * 4;
    float4 s = *(const float4*)&redb[(0 * 8 + r) * 256 + dg];
#pragma unroll
    for (int w = 1; w < 8; ++w) {
      const float4 p = *(const float4*)&redb[(w * 8 + r) * 256 + dg];
      s.x += p.x; s.y += p.y; s.z += p.z; s.w += p.w;
    }
    const float4 x0 = *(const float4*)&x0s[r][dg];
    const float4 bb = *(const float4*)&b2f[dg];
    float4 e;
    e.x = (x0.x + s.x) + bb.x; e.y = (x0.y + s.y) + bb.y;
    e.z = (x0.z + s.z) + bb.z; e.w = (x0.w + s.w) + bb.w;
    *(float4*)&ws[OFF_ENC + (wg * 8 + r) * Dc + dg] = e;
    *(float4*)&encs[r][dg] = e;
  }
  __syncthreads();

  {
    const int f = tid & 255;
    const int rh = tid >> 8;
    float g[4];
    const float be1f = be1[f];
#pragma unroll
    for (int rr = 0; rr < 4; ++rr) g[rr] = be1f;
    for (int c = 0; c < Dc; ++c) {
      const float w = We1[c * Dc + f];
#pragma unroll
      for (int rr = 0; rr < 4; ++rr) g[rr] = fmaf(encs[rh * 4 + rr][c], w, g[rr]);
    }
    const float w2 = We2[f];
#pragma unroll
    for (int rr = 0; rr < 4; ++rr) {
      float p = fmaxf(g[rr], 0.f) * w2;
#pragma unroll
      for (int off = 32; off; off >>= 1) p += __shfl_down(p, off, 64);
      if (lane == 0) zred[wv][rr] = p;
    }
  }
  __syncthreads();
  if (tid < 8) {
    const int r = tid;
    const int wb = (r < 4) ? 0 : 4;
    const int rl = r & 3;
    const float z = ((zred[wb + 0][rl] + zred[wb + 1][rl]) + zred[wb + 2][rl]) +
                    zred[wb + 3][rl];
    ws[OFF_Z + wg * 8 + r] = z + be2[0];
  }
}

extern "C" void kernel_launch(void* const* d_in, const int* in_sizes, int n_in,
                              void* d_out, int out_size, void* d_ws, size_t ws_size,
                              hipStream_t stream) {
  const float* frames = (const float*)d_in[0];
  const float* cls    = (const float*)d_in[1];
  const float* Wq     = (const float*)d_in[2];
  const float* bq     = (const float*)d_in[3];
  const float* Wk     = (const float*)d_in[4];
  const float* bk     = (const float*)d_in[5];
  const float* Wv     = (const float*)d_in[6];
  const float* bv     = (const float*)d_in[7];
  const float* Wo     = (const float*)d_in[8];
  const float* bo     = (const float*)d_in[9];
  const float* g1     = (const float*)d_in[10];
  const float* b1     = (const float*)d_in[11];
  const float* g2     = (const float*)d_in[12];
  const float* b2     = (const float*)d_in[13];
  const float* W1     = (const float*)d_in[14];
  const float* b1f    = (const float*)d_in[15];
  const float* W2     = (const float*)d_in[16];
  const float* b2f    = (const float*)d_in[17];
  const float* We1    = (const float*)d_in[18];
  const float* be1    = (const float*)d_in[19];
  const float* We2    = (const float*)d_in[20];
  const float* be2    = (const float*)d_in[21];
  float* ws = (float*)d_ws;
  float* out = (float*)d_out;

  const size_t need = (size_t)(OFF_CNT + NRB + 1) * sizeof(float);
  const int main_path = (ws_size >= need);

  k_prep<<<Bc * Tc + 1, 256, 0, stream>>>(frames, cls, Wq, bq, Wk, bk, Wv, bv, Wo,
                                          g1, b1, ws, main_path);
  if (main_path) {
    k_attn<<<Bc * Tc, 256, 0, stream>>>(cls, bo, g2, b2, ws);
    k_fzze<<<NT_FZ, 256, 0, stream>>>(W1, b1f, W2, b2f, We1, be1, We2, be2, ws, out);
  } else {
    k_fused<<<Bc * Tc, 512, 0, stream>>>(cls, bo, g2, b2, W1, b1f, W2, b2f, We1, be1, We2, be2, ws);
    k_emit<<<Bc, 256, 0, stream>>>(ws, out);
  }
}

// Round 8
// 236.511 us; speedup vs baseline: 1.3743x; 1.3743x over previous
//
#include <hip/hip_runtime.h>

#define DEV __device__ __forceinline__

constexpr int Bc = 2, Tc = 128, Dc = 256, Lc = 8, Hc = 4, DH = 64, Fc = 2048;
constexpr float EPS = 1e-5f, SCALE = 0.125f;  // 1/sqrt(64)
constexpr int NROWS = Bc * Tc * Lc;           // 2048 candidate rows
constexpr int SLAB = NROWS * Dc;              // 524288 floats

// ---- workspace layout (float offsets) ----
constexpr int OFF_K     = 0;                        // B*T*D frame keys
constexpr int OFF_VWOH  = OFF_K + Bc * Tc * Dc;     // B*T*H*D per-head v@Wo partials
constexpr int OFF_QCLS  = OFF_VWOH + Bc * Tc * Hc * Dc;
constexpr int OFF_KCLS  = OFF_QCLS + Dc;
constexpr int OFF_VWOHC = OFF_KCLS + Dc;            // H*D
constexpr int OFF_ENC   = OFF_VWOHC + Hc * Dc;      // B*T*L*D encoder CLS outputs
constexpr int OFF_Z     = OFF_ENC + SLAB;           // B*T*L eoc logits
// total ~0.86M floats ~= 3.4 MB

DEV int imin(int a, int b) { return a < b ? a : b; }

// block = 256 threads (4 waves). red must be shared float[4].
DEV float blockReduceSum(float v, float* red) {
#pragma unroll
  for (int off = 32; off; off >>= 1) v += __shfl_down(v, off, 64);
  const int lane = threadIdx.x & 63;
  const int w = threadIdx.x >> 6;
  __syncthreads();  // protect red from previous use
  if (lane == 0) red[w] = v;
  __syncthreads();
  return red[0] + red[1] + red[2] + red[3];
}

// ---- K1: one row per block. LN1 + k/v projections + per-head v@Wo; q for CLS row. ----
__global__ __launch_bounds__(256) void k_prep(
    const float* __restrict__ frames, const float* __restrict__ cls,
    const float* __restrict__ Wq, const float* __restrict__ bq,
    const float* __restrict__ Wk, const float* __restrict__ bk,
    const float* __restrict__ Wv, const float* __restrict__ bv,
    const float* __restrict__ Wo,
    const float* __restrict__ g1, const float* __restrict__ b1,
    float* __restrict__ ws) {
  __shared__ float hsm[Dc];
  __shared__ float vsm[Dc];
  __shared__ float red[4];
  const int d = threadIdx.x;
  const int r = blockIdx.x;  // 0..B*T-1 frames, B*T = cls

  const float x = (r < Bc * Tc) ? frames[r * Dc + d] : cls[d];
  const float s = blockReduceSum(x, red);
  const float m = s * (1.0f / Dc);
  const float c = x - m;
  const float var = blockReduceSum(c * c, red) * (1.0f / Dc);
  hsm[d] = c * (1.0f / sqrtf(var + EPS)) * g1[d] + b1[d];
  __syncthreads();

  float ka = bk[d], va = bv[d];
  for (int c2 = 0; c2 < Dc; ++c2) {
    const float h = hsm[c2];
    ka = fmaf(h, Wk[c2 * Dc + d], ka);
    va = fmaf(h, Wv[c2 * Dc + d], va);
  }
  if (r < Bc * Tc) ws[OFF_K + r * Dc + d] = ka;
  else             ws[OFF_KCLS + d] = ka;
  vsm[d] = va;
  __syncthreads();

#pragma unroll
  for (int hh = 0; hh < Hc; ++hh) {
    float acc = 0.f;
    for (int c2 = 0; c2 < DH; ++c2)
      acc = fmaf(vsm[hh * DH + c2], Wo[(hh * DH + c2) * Dc + d], acc);
    if (r < Bc * Tc) ws[OFF_VWOH + r * (Hc * Dc) + hh * Dc + d] = acc;
    else             ws[OFF_VWOHC + hh * Dc + d] = acc;
  }
  if (r == Bc * Tc) {
    float qa = bq[d];
    for (int c2 = 0; c2 < Dc; ++c2) qa = fmaf(hsm[c2], Wq[c2 * Dc + d], qa);
    ws[OFF_QCLS + d] = qa;
  }
}

// ---- K2: FULLY FUSED per (b,i) (round-0 verified structure; FFN loops now use
// 8-deep k-batches + branchless 1-deep W-prefetch, R6-proven on identical loop
// shape. Per-accumulator fma chains unchanged (c/kk ascending) -> bit-exact. ----
__global__ __launch_bounds__(512) void k_fused(
    const float* __restrict__ cls, const float* __restrict__ bo,
    const float* __restrict__ g2, const float* __restrict__ b2,
    const float* __restrict__ W1, const float* __restrict__ b1f,
    const float* __restrict__ W2, const float* __restrict__ b2f,
    const float* __restrict__ We1, const float* __restrict__ be1,
    const float* __restrict__ We2, const float* __restrict__ be2,
    float* __restrict__ ws) {
  const int wg = blockIdx.x;  // b*T + i
  const int i = wg & (Tc - 1);
  const int tid = threadIdx.x;
  const int wv = tid >> 6, lane = tid & 63;
  const int lmax = imin(Tc - i, Lc);

  __shared__ __align__(16) float ts[8][2048];   // 64KB; aliased as redb[8][8][256]
  __shared__ __align__(16) float h2s[8][256];   // 8KB
  __shared__ __align__(16) float x0s[8][256];   // 8KB
  __shared__ __align__(16) float encs[8][256];  // 8KB
  __shared__ float sv[Hc][Lc + 1];
  __shared__ float aP[Lc][Hc][Lc + 1];
  __shared__ __align__(16) float redA[Lc][4];
  __shared__ __align__(16) float redB[Lc][4];
  __shared__ float zred[8][4];

  // ---- scores: waves 0-3, wave = head ----
  if (tid < 256) {
    const int hh = tid >> 6;
    const float qv = ws[OFF_QCLS + hh * DH + lane];
    for (int j = 0; j <= Lc; ++j) {
      float p = 0.f;
      if (j == 0) p = qv * ws[OFF_KCLS + hh * DH + lane];
      else if (j - 1 < lmax) p = qv * ws[OFF_K + (wg + j - 1) * Dc + hh * DH + lane];
#pragma unroll
      for (int off = 32; off; off >>= 1) p += __shfl_down(p, off, 64);
      if (lane == 0) sv[hh][j] = p * SCALE;
    }
  }
  __syncthreads();

  // ---- softmax per candidate length ----
  if (tid < Lc * Hc) {
    const int l = (tid >> 2) + 1, h4 = tid & 3;
    if (l <= lmax) {
      float mx = -1e30f;
      for (int j = 0; j <= l; ++j) mx = fmaxf(mx, sv[h4][j]);
      float den = 0.f;
      for (int j = 0; j <= l; ++j) den += expf(sv[h4][j] - mx);
      const float inv = 1.f / den;
      for (int j = 0; j <= l; ++j) aP[l - 1][h4][j] = expf(sv[h4][j] - mx) * inv;
    }
  }
  __syncthreads();

  // ---- x0 accumulation + LN round 1 (threads 0-255, d = tid) ----
  float x0v[Lc];
  if (tid < 256) {
    const int d = tid;
    const float base = cls[d] + bo[d];
#pragma unroll
    for (int l = 0; l < Lc; ++l) x0v[l] = base;
    for (int j = 0; j <= lmax; ++j) {
      const float* vwp = (j == 0) ? (ws + OFF_VWOHC)
                                  : (ws + OFF_VWOH + (wg + j - 1) * (Hc * Dc));
      for (int h4 = 0; h4 < Hc; ++h4) {
        const float w = vwp[h4 * Dc + d];
        const int lstart = (j == 0) ? 1 : j;
        for (int l = lstart; l <= lmax; ++l) x0v[l - 1] = fmaf(aP[l - 1][h4][j], w, x0v[l - 1]);
      }
    }
#pragma unroll
    for (int l = 0; l < Lc; ++l) {
      float p = x0v[l];
#pragma unroll
      for (int off = 32; off; off >>= 1) p += __shfl_down(p, off, 64);
      if (lane == 0) redA[l][tid >> 6] = p;
    }
  }
  __syncthreads();

  float mean[Lc];
  if (tid < 256) {
#pragma unroll
    for (int l = 0; l < Lc; ++l) {
      const float4 s4 = *(const float4*)redA[l];
      mean[l] = (s4.x + s4.y + s4.z + s4.w) * (1.f / Dc);
    }
#pragma unroll
    for (int l = 0; l < Lc; ++l) {
      const float cv = x0v[l] - mean[l];
      float p = cv * cv;
#pragma unroll
      for (int off = 32; off; off >>= 1) p += __shfl_down(p, off, 64);
      if (lane == 0) redB[l][tid >> 6] = p;
    }
  }
  __syncthreads();

  if (tid < 256) {
    const int d = tid;
    const float g2d = g2[d], b2d = b2[d];
    for (int l = 1; l <= lmax; ++l) {
      const float4 s4 = *(const float4*)redB[l - 1];
      const float var = (s4.x + s4.y + s4.z + s4.w) * (1.f / Dc);
      const float rstd = 1.f / sqrtf(var + EPS);
      h2s[l - 1][d] = (x0v[l - 1] - mean[l - 1]) * rstd * g2d + b2d;
      x0s[l - 1][d] = x0v[l - 1];
    }
    for (int l = lmax + 1; l <= Lc; ++l) {
      h2s[l - 1][d] = 0.f;
      x0s[l - 1][d] = 0.f;
    }
  }
  __syncthreads();

  // ---- FFN phase 1: T = relu(h2 @ W1 + b1f); 8-deep batch + 1-deep prefetch ----
  const int fg = tid * 4;  // thread owns 4 f-cols of 2048
  float t[8][4];
  {
    const float4 bb = *(const float4*)&b1f[fg];
#pragma unroll
    for (int r = 0; r < 8; ++r) { t[r][0] = bb.x; t[r][1] = bb.y; t[r][2] = bb.z; t[r][3] = bb.w; }
  }
  {
    const float* Wp = W1 + fg;
    float4 wn[8];
#pragma unroll
    for (int k = 0; k < 8; ++k) wn[k] = *(const float4*)&Wp[k * Fc];
    for (int c = 0; c < Dc; c += 8) {
      float4 wc[8];
#pragma unroll
      for (int k = 0; k < 8; ++k) wc[k] = wn[k];
      {  // branchless 1-deep prefetch (re-reads last rows on final iter)
        const float* Wn = Wp + imin(c + 8, Dc - 8) * Fc;
#pragma unroll
        for (int k = 0; k < 8; ++k) wn[k] = *(const float4*)&Wn[k * Fc];
      }
#pragma unroll
      for (int r = 0; r < 8; ++r) {
        const float4 ha = *(const float4*)&h2s[r][c];
        const float4 hb = *(const float4*)&h2s[r][c + 4];
        const float hv[8] = {ha.x, ha.y, ha.z, ha.w, hb.x, hb.y, hb.z, hb.w};
#pragma unroll
        for (int k = 0; k < 8; ++k) {
          t[r][0] = fmaf(hv[k], wc[k].x, t[r][0]);
          t[r][1] = fmaf(hv[k], wc[k].y, t[r][1]);
          t[r][2] = fmaf(hv[k], wc[k].z, t[r][2]);
          t[r][3] = fmaf(hv[k], wc[k].w, t[r][3]);
        }
      }
    }
  }
#pragma unroll
  for (int r = 0; r < 8; ++r) {
    float4 v;
    v.x = fmaxf(t[r][0], 0.f); v.y = fmaxf(t[r][1], 0.f);
    v.z = fmaxf(t[r][2], 0.f); v.w = fmaxf(t[r][3], 0.f);
    *(float4*)&ts[r][fg] = v;
  }
  __syncthreads();

  // ---- FFN phase 2: u = T @ W2; wave wv owns k-slice; 8-deep + prefetch ----
  const int d4 = lane * 4;
  float u[8][4];
#pragma unroll
  for (int r = 0; r < 8; ++r) { u[r][0] = 0.f; u[r][1] = 0.f; u[r][2] = 0.f; u[r][3] = 0.f; }
  {
    const float* Wp = W2 + (wv * 256) * Dc + d4;
    float4 wn[8];
#pragma unroll
    for (int k = 0; k < 8; ++k) wn[k] = *(const float4*)&Wp[k * Dc];
    for (int kk = 0; kk < 256; kk += 8) {
      const int kg = wv * 256 + kk;
      float4 wc[8];
#pragma unroll
      for (int k = 0; k < 8; ++k) wc[k] = wn[k];
      {
        const float* Wn = Wp + imin(kk + 8, 256 - 8) * Dc;
#pragma unroll
        for (int k = 0; k < 8; ++k) wn[k] = *(const float4*)&Wn[k * Dc];
      }
#pragma unroll
      for (int r = 0; r < 8; ++r) {
        const float4 ha = *(const float4*)&ts[r][kg];
        const float4 hb = *(const float4*)&ts[r][kg + 4];
        const float hv[8] = {ha.x, ha.y, ha.z, ha.w, hb.x, hb.y, hb.z, hb.w};
#pragma unroll
        for (int k = 0; k < 8; ++k) {
          u[r][0] = fmaf(hv[k], wc[k].x, u[r][0]);
          u[r][1] = fmaf(hv[k], wc[k].y, u[r][1]);
          u[r][2] = fmaf(hv[k], wc[k].z, u[r][2]);
          u[r][3] = fmaf(hv[k], wc[k].w, u[r][3]);
        }
      }
    }
  }
  __syncthreads();  // all ts reads done before aliasing as redb

  // ---- deterministic 8-partial reduce (redb[8][8][256] aliases ts) ----
  float* redb = &ts[0][0];
#pragma unroll
  for (int r = 0; r < 8; ++r) {
    float4 v; v.x = u[r][0]; v.y = u[r][1]; v.z = u[r][2]; v.w = u[r][3];
    *(float4*)&redb[(wv * 8 + r) * 256 + d4] = v;
  }
  __syncthreads();

  // ---- enc = x0 + U + b2f; thread owns one (row, d4) group ----
  {
    const int r = tid >> 6;         // row = wave id
    const int dg = (tid & 63) * 4;  // d-group
    float4 s = *(const float4*)&redb[(0 * 8 + r) * 256 + dg];
#pragma unroll
    for (int w = 1; w < 8; ++w) {
      const float4 p = *(const float4*)&redb[(w * 8 + r) * 256 + dg];
      s.x += p.x; s.y += p.y; s.z += p.z; s.w += p.w;
    }
    const float4 x0 = *(const float4*)&x0s[r][dg];
    const float4 bb = *(const float4*)&b2f[dg];
    float4 e;
    e.x = (x0.x + s.x) + bb.x; e.y = (x0.y + s.y) + bb.y;
    e.z = (x0.z + s.z) + bb.z; e.w = (x0.w + s.w) + bb.w;
    *(float4*)&ws[OFF_ENC + (wg * 8 + r) * Dc + dg] = e;
    *(float4*)&encs[r][dg] = e;
  }
  __syncthreads();

  // ---- z = relu(enc@We1+be1)@We2 + be2 ----
  {
    const int f = tid & 255;  // waves 0-3: rows 0-3; waves 4-7: rows 4-7
    const int rh = tid >> 8;
    float g[4];
    const float be1f = be1[f];
#pragma unroll
    for (int rr = 0; rr < 4; ++rr) g[rr] = be1f;
    for (int c = 0; c < Dc; ++c) {
      const float w = We1[c * Dc + f];
#pragma unroll
      for (int rr = 0; rr < 4; ++rr) g[rr] = fmaf(encs[rh * 4 + rr][c], w, g[rr]);
    }
    const float w2 = We2[f];
#pragma unroll
    for (int rr = 0; rr < 4; ++rr) {
      float p = fmaxf(g[rr], 0.f) * w2;
#pragma unroll
      for (int off = 32; off; off >>= 1) p += __shfl_down(p, off, 64);
      if (lane == 0) zred[wv][rr] = p;
    }
  }
  __syncthreads();
  if (tid < 8) {
    const int r = tid;
    const int wb = (r < 4) ? 0 : 4;
    const int rl = r & 3;
    const float z = ((zred[wb + 0][rl] + zred[wb + 1][rl]) + zred[wb + 2][rl]) +
                    zred[wb + 3][rl];
    ws[OFF_Z + wg * 8 + r] = z + be2[0];
  }
}

// ---- K3: select lstar (fused) + sequential walk via wave shuffles + emit ----
__global__ __launch_bounds__(256) void k_emit(float* __restrict__ ws, float* __restrict__ out) {
  const int b = blockIdx.x;
  const int tid = threadIdx.x;
  __shared__ int lst[Tc];
  __shared__ int path[Tc];
  __shared__ int cnt_s;
  if (tid < Tc) {
    const int i = tid;
    const int lmax = imin(Tc - i, Lc);
    const float* z = ws + OFF_Z + (b * Tc + i) * Lc;
    int ls = lmax;
    for (int l = 1; l <= lmax; ++l) {
      if (z[l - 1] > 0.f) { ls = l; break; }
    }
    lst[tid] = ls;
  }
  __syncthreads();
  if (tid < 64) {  // wave 0: walk via register shuffles (low-latency chain)
    const int a0 = lst[tid], a1 = lst[64 + tid];
    int cur = 0, s = 0;
    while (cur < Tc) {
      const int l = (cur < 64) ? __shfl(a0, cur, 64) : __shfl(a1, cur - 64, 64);
      if (tid == 0) path[s] = cur * Lc + l - 1;
      ++s;
      cur += l;
    }
    if (tid == 0) cnt_s = s;
  }
  __syncthreads();
  const int c = cnt_s;
  for (int s0 = 0; s0 < Tc; s0 += 8) {
    float v[8];
#pragma unroll
    for (int k = 0; k < 8; ++k) {
      const int s = s0 + k;
      v[k] = (s < c) ? ws[OFF_ENC + (b * Tc * Lc + path[s]) * Dc + tid] : 0.f;
    }
#pragma unroll
    for (int k = 0; k < 8; ++k) out[(b * Tc + s0 + k) * Dc + tid] = v[k];
  }
  if (tid == 0) out[Bc * Tc * Dc + b] = (float)c;
}

extern "C" void kernel_launch(void* const* d_in, const int* in_sizes, int n_in,
                              void* d_out, int out_size, void* d_ws, size_t ws_size,
                              hipStream_t stream) {
  const float* frames = (const float*)d_in[0];
  const float* cls    = (const float*)d_in[1];
  const float* Wq     = (const float*)d_in[2];
  const float* bq     = (const float*)d_in[3];
  const float* Wk     = (const float*)d_in[4];
  const float* bk     = (const float*)d_in[5];
  const float* Wv     = (const float*)d_in[6];
  const float* bv     = (const float*)d_in[7];
  const float* Wo     = (const float*)d_in[8];
  const float* bo     = (const float*)d_in[9];
  const float* g1     = (const float*)d_in[10];
  const float* b1     = (const float*)d_in[11];
  const float* g2     = (const float*)d_in[12];
  const float* b2     = (const float*)d_in[13];
  const float* W1     = (const float*)d_in[14];
  const float* b1f    = (const float*)d_in[15];
  const float* W2     = (const float*)d_in[16];
  const float* b2f    = (const float*)d_in[17];
  const float* We1    = (const float*)d_in[18];
  const float* be1    = (const float*)d_in[19];
  const float* We2    = (const float*)d_in[20];
  const float* be2    = (const float*)d_in[21];
  float* ws = (float*)d_ws;
  float* out = (float*)d_out;

  k_prep<<<Bc * Tc + 1, 256, 0, stream>>>(frames, cls, Wq, bq, Wk, bk, Wv, bv, Wo, g1, b1, ws);
  k_fused<<<Bc * Tc, 512, 0, stream>>>(cls, bo, g2, b2, W1, b1f, W2, b2f, We1, be1, We2, be2, ws);
  k_emit<<<Bc, 256, 0, stream>>>(ws, out);
}